// Round 3
// baseline (8744.040 us; speedup 1.0000x reference)
//
#include <hip/hip_runtime.h>

// VQ nearest-codebook, fp32, z-in-SGPR / e-in-LDS design.
// score(n,k) = 0.5*|e_k|^2 - z_n.e_k  (monotone in squared distance)
//
// vq_main: block = 32 tokens x 512 codes (16 K-splits). 4 waves; each wave
//   owns 8 tokens (wave-uniform -> z via s_load into SGPRs) and all 512
//   codes (8 per lane). acc[8][8] persists across the full c loop -> z
//   loaded once per chunk. LDS holds only the e-chunk [2 f4][512 codes],
//   double-buffered; all LDS ops lane-consecutive float4 (conflict-free).
// vq_final: combine 16 split candidates per token, gather embedding row.

#define C 256
#define C4 64            // float4 per row
#define TPB 256
#define BT 32            // tokens per block
#define WT 8             // tokens per wave
#define BC 512           // codes per block (one per-lane x 8 groups)
#define NSPLIT 16
#define NCK 32           // 256 c / 8 c per chunk

__global__ __launch_bounds__(64) void vq_norms(const float* __restrict__ emb,
                                               float* __restrict__ hn) {
    const int k = blockIdx.x;
    const int lane = threadIdx.x;
    const float4 v = *reinterpret_cast<const float4*>(emb + (size_t)k * C + lane * 4);
    float s = v.x * v.x + v.y * v.y + v.z * v.z + v.w * v.w;
    #pragma unroll
    for (int off = 32; off; off >>= 1) s += __shfl_down(s, off);
    if (lane == 0) hn[k] = 0.5f * s;
}

__device__ __forceinline__ void fma8(float (&acc)[WT][8], int m,
                                     const float4 (&zs)[WT], const float4 ev) {
    #pragma unroll
    for (int j = 0; j < WT; ++j) {
        acc[j][m] = fmaf(zs[j].x, ev.x, acc[j][m]);
        acc[j][m] = fmaf(zs[j].y, ev.y, acc[j][m]);
        acc[j][m] = fmaf(zs[j].z, ev.z, acc[j][m]);
        acc[j][m] = fmaf(zs[j].w, ev.w, acc[j][m]);
    }
}

__global__ __launch_bounds__(TPB) void vq_main(
    const float* __restrict__ z, const float* __restrict__ emb,
    const float* __restrict__ hn, float* __restrict__ bs,
    int* __restrict__ bia, int Ntok) {
    __shared__ float4 et[2][2][BC];   // [buf][f4-half][code]  32 KB

    const int tid = threadIdx.x;
    const int lane = tid & 63;
    const int wid = __builtin_amdgcn_readfirstlane(tid >> 6);
    const int sp = blockIdx.x & (NSPLIT - 1);
    const int tb = blockIdx.x >> 4;
    const int cbase = sp * BC;
    const int token0 = tb * BT + wid * WT;
    const float* zw = z + (size_t)token0 * C;             // wave-uniform
    const float4* ef4 = reinterpret_cast<const float4*>(emb);

    // stage chunk 0
    #pragma unroll
    for (int it = 0; it < 2; ++it) {
        const int code = it * TPB + tid;
        const float4* g = ef4 + (size_t)(cbase + code) * C4;
        et[0][0][code] = g[0];
        et[0][1][code] = g[1];
    }
    __syncthreads();

    float acc[WT][8] = {};

    #pragma unroll 2
    for (int ck = 0; ck < NCK; ++ck) {
        const int nb = ck & 1;
        // prefetch next e-chunk into registers
        float4 ra[2], rb[2];
        if (ck < NCK - 1) {
            #pragma unroll
            for (int it = 0; it < 2; ++it) {
                const int code = it * TPB + tid;
                const float4* g = ef4 + (size_t)(cbase + code) * C4 + (ck + 1) * 2;
                ra[it] = g[0];
                rb[it] = g[1];
            }
        }
        // z scalars for this chunk (wave-uniform -> s_load)
        float4 za[WT], zb[WT];
        #pragma unroll
        for (int j = 0; j < WT; ++j) {
            const float4* p = reinterpret_cast<const float4*>(zw + j * C) + ck * 2;
            za[j] = p[0];
            zb[j] = p[1];
        }
        // compute: 2 f4-halves x 8 code-groups x 8 tokens x 4 c
        #pragma unroll
        for (int m = 0; m < 8; ++m) fma8(acc, m, za, et[nb][0][m * 64 + lane]);
        #pragma unroll
        for (int m = 0; m < 8; ++m) fma8(acc, m, zb, et[nb][1][m * 64 + lane]);

        if (ck < NCK - 1) {
            #pragma unroll
            for (int it = 0; it < 2; ++it) {
                const int code = it * TPB + tid;
                et[nb ^ 1][0][code] = ra[it];
                et[nb ^ 1][1][code] = rb[it];
            }
        }
        __syncthreads();
    }

    // epilogue: per-token argmin over this wave's 512 codes
    float hv[8];
    #pragma unroll
    for (int m = 0; m < 8; ++m) hv[m] = hn[cbase + m * 64 + lane];

    #pragma unroll 1
    for (int j = 0; j < WT; ++j) {
        float s = 3.4e38f;
        int bi = 0;
        #pragma unroll
        for (int m = 0; m < 8; ++m) {   // ascending code within lane
            const float sc = hv[m] - acc[j][m];
            const int code = cbase + m * 64 + lane;
            if (sc < s) { s = sc; bi = code; }
        }
        #pragma unroll
        for (int off = 32; off; off >>= 1) {
            const float os = __shfl_xor(s, off);
            const int oi = __shfl_xor(bi, off);
            if (os < s || (os == s && oi < bi)) { s = os; bi = oi; }
        }
        if (lane == 0) {
            const int token = token0 + j;
            bs[sp * Ntok + token] = s;
            bia[sp * Ntok + token] = bi;
        }
    }
}

__global__ __launch_bounds__(256) void vq_final(const float* __restrict__ emb,
                                                const float* __restrict__ bs,
                                                const int* __restrict__ bia,
                                                float* __restrict__ out, int Ntok) {
    const int token = blockIdx.x * 4 + (threadIdx.x >> 6);
    const int lane = threadIdx.x & 63;
    float best = 3.4e38f;
    int b = 0;
    #pragma unroll
    for (int s = 0; s < NSPLIT; ++s) {   // ascending split = ascending codes
        const float sc = bs[s * Ntok + token];
        const int ii = bia[s * Ntok + token];
        if (sc < best) { best = sc; b = ii; }
    }
    const float4* ef4 = reinterpret_cast<const float4*>(emb);
    float4* of4 = reinterpret_cast<float4*>(out);
    of4[(size_t)token * C4 + lane] = ef4[(size_t)b * C4 + lane];
}

extern "C" void kernel_launch(void* const* d_in, const int* in_sizes, int n_in,
                              void* d_out, int out_size, void* d_ws, size_t ws_size,
                              hipStream_t stream) {
    const float* z = (const float*)d_in[0];
    const float* emb = (const float*)d_in[1];
    float* out = (float*)d_out;

    const int N = in_sizes[0] / C;   // 16384 tokens
    const int K = in_sizes[1] / C;   // 8192 codes

    float* hn = (float*)d_ws;                 // K floats
    float* bs = hn + K;                       // NSPLIT*N floats
    int* bia = (int*)(bs + NSPLIT * N);       // NSPLIT*N ints (~2.1 MB total)

    vq_norms<<<K, 64, 0, stream>>>(emb, hn);
    vq_main<<<(N / BT) * NSPLIT, TPB, 0, stream>>>(z, emb, hn, bs, bia, N);
    vq_final<<<N / 4, 256, 0, stream>>>(emb, bs, bia, out, N);
}